// Round 1
// baseline (3717.854 us; speedup 1.0000x reference)
//
#include <hip/hip_runtime.h>
#include <hip/hip_bf16.h>
#include <math.h>

// ---------------------------------------------------------------------------
// Model dims (fixed by the reference)
// ---------------------------------------------------------------------------
// B=2, Cn=3, HI=WI=224, GRID=14, PATCH=16, S=196, P=256, D=384, H_TOK=4
// DEPTH=12, H_VIT=6 (dh=64), HID=1536, NCLS=1000

static __device__ __forceinline__ float gelu_exact(float v) {
    return 0.5f * v * (1.0f + erff(v * 0.70710678118654752440f));
}

// ---------------------------------------------------------------------------
// prep: W2[1152][3] = ap_in_w @ fp_w ; b2[1152] = ap_in_b + ap_in_w @ fp_b
// ---------------------------------------------------------------------------
__global__ __launch_bounds__(256) void prep_w2_k(
    const float* __restrict__ ap_in_w, const float* __restrict__ ap_in_b,
    const float* __restrict__ fp_w, const float* __restrict__ fp_b,
    float* __restrict__ W2, float* __restrict__ b2)
{
    int o = blockIdx.x * 256 + threadIdx.x;
    if (o >= 1152) return;
    const float* ar = ap_in_w + (long)o * 384;
    float a0 = 0.f, a1 = 0.f, a2 = 0.f, ab = ap_in_b[o];
    for (int d = 0; d < 384; ++d) {
        float aw = ar[d];
        a0 = fmaf(aw, fp_w[d*3+0], a0);
        a1 = fmaf(aw, fp_w[d*3+1], a1);
        a2 = fmaf(aw, fp_w[d*3+2], a2);
        ab = fmaf(aw, fp_b[d], ab);
    }
    W2[o*3+0] = a0; W2[o*3+1] = a1; W2[o*3+2] = a2; b2[o] = ab;
}

// ---------------------------------------------------------------------------
// prep per-head bilinear form: s_ij = px_i^T G px_j + u.px_i + w.px_j + c0
// stored per head as 4 float4 rows: rows 0..2 = (G[c][0..2], u[c]); row3=(w,c0)
// All scaled by 1/sqrt(96).
// ---------------------------------------------------------------------------
__global__ __launch_bounds__(64) void prep_head_k(
    const float* __restrict__ W2, const float* __restrict__ b2,
    float* __restrict__ hGm)
{
    int h = blockIdx.x;
    int lane = threadIdx.x;
    float G00=0,G01=0,G02=0,G10=0,G11=0,G12=0,G20=0,G21=0,G22=0;
    float u0=0,u1=0,u2=0,w0=0,w1=0,w2=0,c0=0;
    for (int d = lane; d < 96; d += 64) {
        int oq = h*96 + d, ok = 384 + h*96 + d;
        float q0=W2[oq*3],q1=W2[oq*3+1],q2=W2[oq*3+2];
        float k0=W2[ok*3],k1=W2[ok*3+1],k2=W2[ok*3+2];
        float bq=b2[oq], bk=b2[ok];
        G00=fmaf(q0,k0,G00); G01=fmaf(q0,k1,G01); G02=fmaf(q0,k2,G02);
        G10=fmaf(q1,k0,G10); G11=fmaf(q1,k1,G11); G12=fmaf(q1,k2,G12);
        G20=fmaf(q2,k0,G20); G21=fmaf(q2,k1,G21); G22=fmaf(q2,k2,G22);
        u0=fmaf(q0,bk,u0); u1=fmaf(q1,bk,u1); u2=fmaf(q2,bk,u2);
        w0=fmaf(k0,bq,w0); w1=fmaf(k1,bq,w1); w2=fmaf(k2,bq,w2);
        c0=fmaf(bq,bk,c0);
    }
    float vals[16] = {G00,G01,G02,u0, G10,G11,G12,u1, G20,G21,G22,u2, w0,w1,w2,c0};
    const float sc = 0.10206207261596577f; // 1/sqrt(96)
    #pragma unroll
    for (int q = 0; q < 16; ++q) {
        float v = vals[q];
        for (int off = 32; off; off >>= 1) v += __shfl_down(v, off);
        if (lane == 0) hGm[h*16 + q] = v * sc;
    }
}

// ---------------------------------------------------------------------------
// Tokenizer attention, one block per (segment s, head h, batch b).
// Produces pooled_pre[b*196+s][h*96 + d] = mean_i(attn row i) @ V  (pre out-proj)
// Exact math: 3 cheap sweeps (row-max, row-sumexp, col-sum A_j), then
// pooled[d] = (W2v[d] . t)/256 + b2v[d] with t_c = sum_j A_j px[c][j].
// ---------------------------------------------------------------------------
__global__ __launch_bounds__(256) void tok_attn_k(
    const float* __restrict__ img, const float* __restrict__ hGm,
    const float* __restrict__ W2, const float* __restrict__ b2,
    float* __restrict__ pooled)
{
    int s = blockIdx.x, h = blockIdx.y, b = blockIdx.z;
    int t = threadIdx.x;
    __shared__ float4 pxm[256];   // px0,px1,px2, (later) row max
    __shared__ float4 ylds[256];  // Y0..Y3 per pixel j
    __shared__ float  rl[256];    // 1/l_i
    __shared__ float  Ash[256];   // col sums A_j
    __shared__ float  tsum[3];

    int gy = s / 14, gx = s - gy*14;
    int row = gy*16 + (t >> 4), col = gx*16 + (t & 15);
    long base = ((long)b*3*224 + row)*224 + col;
    float p0 = img[base];
    float p1 = img[base + 224*224];
    float p2 = img[base + 2*224*224];

    const float4* M4 = reinterpret_cast<const float4*>(hGm) + h*4;
    float4 r0 = M4[0], r1 = M4[1], r2 = M4[2], r3 = M4[3];
    float y0 = fmaf(p0,r0.x, fmaf(p1,r0.y, fmaf(p2,r0.z, r0.w)));
    float y1 = fmaf(p0,r1.x, fmaf(p1,r1.y, fmaf(p2,r1.z, r1.w)));
    float y2 = fmaf(p0,r2.x, fmaf(p1,r2.y, fmaf(p2,r2.z, r2.w)));
    float y3 = fmaf(p0,r3.x, fmaf(p1,r3.y, fmaf(p2,r3.z, r3.w)));
    ylds[t] = make_float4(y0,y1,y2,y3);
    pxm[t]  = make_float4(p0,p1,p2,0.f);
    __syncthreads();

    // pass 1: row max
    float mx = -1e30f;
    #pragma unroll 4
    for (int j = 0; j < 256; ++j) {
        float4 Y = ylds[j];
        float scr = fmaf(p0,Y.x, fmaf(p1,Y.y, fmaf(p2,Y.z, Y.w)));
        mx = fmaxf(mx, scr);
    }
    // pass 2: row sum of exp
    float l = 0.f;
    #pragma unroll 4
    for (int j = 0; j < 256; ++j) {
        float4 Y = ylds[j];
        float scr = fmaf(p0,Y.x, fmaf(p1,Y.y, fmaf(p2,Y.z, Y.w)));
        l += __expf(scr - mx);
    }
    pxm[t].w = mx;
    rl[t] = 1.f / l;
    __syncthreads();

    // pass 3: column sums A_j (thread t owns column j=t; its own Y in regs)
    float Aj = 0.f;
    #pragma unroll 4
    for (int i = 0; i < 256; ++i) {
        float4 q = pxm[i];
        float scr = fmaf(q.x,y0, fmaf(q.y,y1, fmaf(q.z,y2, y3)));
        Aj += __expf(scr - q.w) * rl[i];
    }
    Ash[t] = Aj;
    __syncthreads();

    // reduce t_c = sum_j A_j * px[c][j]  (wave w handles channel c=w)
    int w = t >> 6, lane = t & 63;
    if (w < 3) {
        float prt = 0.f;
        for (int j = lane; j < 256; j += 64) {
            const float* pj = reinterpret_cast<const float*>(&pxm[j]);
            prt = fmaf(Ash[j], pj[w], prt);
        }
        for (int off = 32; off; off >>= 1) prt += __shfl_down(prt, off);
        if (lane == 0) tsum[w] = prt;
    }
    __syncthreads();

    if (t < 96) {
        int o = 768 + h*96 + t; // V rows of in-proj
        float v = (W2[o*3]*tsum[0] + W2[o*3+1]*tsum[1] + W2[o*3+2]*tsum[2]) * (1.f/256.f)
                  + b2[o];
        pooled[((long)(b*196 + s))*384 + h*96 + t] = v;
    }
}

// ---------------------------------------------------------------------------
// Generic f32 GEMM: C = alpha * (A @ op(W)) + bias (+GELU) (+resid)
//   A[M,K] lda ; W row n holds K values (ldw) unless BT (then W[k*ldw+n])
//   Batched via grid.z: z -> (bi=z/H, hi=z%H) with per-operand strides.
//   kchunk>0: split-K partial, hi selects K-slice [hi*kchunk, ...).
// 64x64 tile, BK=16, 256 threads, 4x4 microtile.
// ---------------------------------------------------------------------------
template<bool BT, bool RES, bool GEL>
__global__ __launch_bounds__(256) void gemm64_k(
    const float* __restrict__ A, const float* __restrict__ W,
    const float* __restrict__ bias, const float* __restrict__ resid,
    float* __restrict__ C, int M, int N, int K, int lda, int ldw, int ldc,
    float alpha, int H, long sAb, long sAh, long sWb, long sWh, long sCb, long sCh,
    int kchunk)
{
    __shared__ float As[16][68];
    __shared__ float Bs[16][68];
    int z = blockIdx.z;
    int bi = z / H, hi = z - bi*H;
    A += bi*sAb + hi*sAh;
    W += bi*sWb + hi*sWh;
    long coff = bi*sCb + hi*sCh;
    C += coff;
    const float* R = RES ? (resid + coff) : nullptr;
    int ks = 0, ke = K;
    if (kchunk > 0) { ks = hi * kchunk; ke = min(K, ks + kchunk); }
    int m0 = blockIdx.x * 64, n0 = blockIdx.y * 64;
    int tid = threadIdx.x;
    int tx = tid & 15, ty = tid >> 4;
    float acc[4][4];
    #pragma unroll
    for (int i=0;i<4;++i)
        #pragma unroll
        for (int j=0;j<4;++j) acc[i][j]=0.f;

    for (int k0 = ks; k0 < ke; k0 += 16) {
        #pragma unroll
        for (int e = tid; e < 1024; e += 256) {
            int m = e >> 4, kk = e & 15;
            float v = 0.f;
            if (m0+m < M && k0+kk < ke) v = A[(long)(m0+m)*lda + k0+kk];
            As[kk][m] = v;
        }
        #pragma unroll
        for (int e = tid; e < 1024; e += 256) {
            float v = 0.f;
            if (!BT) {
                int n = e >> 4, kk = e & 15;
                if (n0+n < N && k0+kk < ke) v = W[(long)(n0+n)*ldw + k0+kk];
                Bs[kk][n] = v;
            } else {
                int n = e & 63, kk = e >> 6;
                if (k0+kk < ke && n0+n < N) v = W[(long)(k0+kk)*ldw + n0+n];
                Bs[kk][n] = v;
            }
        }
        __syncthreads();
        #pragma unroll
        for (int kk = 0; kk < 16; ++kk) {
            float4 av = *reinterpret_cast<const float4*>(&As[kk][ty*4]);
            float4 bv = *reinterpret_cast<const float4*>(&Bs[kk][tx*4]);
            float a[4] = {av.x,av.y,av.z,av.w};
            float b[4] = {bv.x,bv.y,bv.z,bv.w};
            #pragma unroll
            for (int i=0;i<4;++i)
                #pragma unroll
                for (int j=0;j<4;++j)
                    acc[i][j] = fmaf(a[i], b[j], acc[i][j]);
        }
        __syncthreads();
    }

    #pragma unroll
    for (int i=0;i<4;++i) {
        int m = m0 + ty*4 + i;
        if (m >= M) continue;
        #pragma unroll
        for (int j=0;j<4;++j) {
            int n = n0 + tx*4 + j;
            if (n >= N) continue;
            float v = acc[i][j] * alpha;
            if (bias) v += bias[n];
            if (GEL) v = gelu_exact(v);
            if (RES) v += R[(long)m*ldc + n];
            C[(long)m*ldc + n] = v;
        }
    }
}

template<bool BT, bool RES, bool GEL>
static void launch_gemm(hipStream_t stream, const float* A, const float* W,
                        const float* bias, const float* resid, float* C,
                        int M, int N, int K, int lda, int ldw, int ldc,
                        float alpha, int gz, int H,
                        long sAb, long sAh, long sWb, long sWh, long sCb, long sCh,
                        int kchunk)
{
    dim3 grid((M+63)/64, (N+63)/64, gz);
    gemm64_k<BT,RES,GEL><<<grid, 256, 0, stream>>>(A, W, bias, resid, C, M, N, K,
        lda, ldw, ldc, alpha, H, sAb, sAh, sWb, sWh, sCb, sCh, kchunk);
}

// ---------------------------------------------------------------------------
// x0 = concat(cls, tok) + pos_embed  -> x[2*197][384]
// ---------------------------------------------------------------------------
__global__ __launch_bounds__(256) void build_x0_k(
    const float* __restrict__ tok, const float* __restrict__ cls,
    const float* __restrict__ pos, float* __restrict__ x)
{
    int idx = blockIdx.x*256 + threadIdx.x;
    if (idx >= 2*197*384) return;
    int d = idx % 384;
    int n = (idx / 384) % 197;
    int b = idx / (384*197);
    float v = (n == 0) ? cls[d] : tok[((long)b*196 + (n-1))*384 + d];
    x[idx] = v + pos[n*384 + d];
}

// ---------------------------------------------------------------------------
// LayerNorm over last dim 384; one block (128 threads) per row.
// ---------------------------------------------------------------------------
__global__ __launch_bounds__(128) void ln_k(
    const float* __restrict__ x, const float* __restrict__ g,
    const float* __restrict__ b, float* __restrict__ y)
{
    long r = blockIdx.x;
    const float* xr = x + r*384;
    int t = threadIdx.x;
    float v0 = xr[t], v1 = xr[t+128], v2 = xr[t+256];
    __shared__ float red[2];
    int lane = t & 63, wid = t >> 6;
    float sm = v0+v1+v2;
    for (int off = 32; off; off >>= 1) sm += __shfl_down(sm, off);
    if (lane == 0) red[wid] = sm;
    __syncthreads();
    float mean = (red[0]+red[1]) * (1.f/384.f);
    __syncthreads();
    float d0=v0-mean, d1=v1-mean, d2=v2-mean;
    float s2 = d0*d0 + d1*d1 + d2*d2;
    for (int off = 32; off; off >>= 1) s2 += __shfl_down(s2, off);
    if (lane == 0) red[wid] = s2;
    __syncthreads();
    float var = (red[0]+red[1]) * (1.f/384.f);
    float rstd = rsqrtf(var + 1e-6f);
    float* yr = y + r*384;
    yr[t]     = d0*rstd*g[t]     + b[t];
    yr[t+128] = d1*rstd*g[t+128] + b[t+128];
    yr[t+256] = d2*rstd*g[t+256] + b[t+256];
}

// ---------------------------------------------------------------------------
// Row softmax over 197 columns, in place. One block per row.
// ---------------------------------------------------------------------------
__global__ __launch_bounds__(256) void softmax_k(float* __restrict__ sc)
{
    long row = blockIdx.x;
    float* sp = sc + row*197;
    int j = threadIdx.x;
    float v = (j < 197) ? sp[j] : -1e30f;
    __shared__ float red[4];
    int lane = j & 63, wid = j >> 6;
    float m = v;
    for (int off = 32; off; off >>= 1) m = fmaxf(m, __shfl_down(m, off));
    if (lane == 0) red[wid] = m;
    __syncthreads();
    m = fmaxf(fmaxf(red[0],red[1]), fmaxf(red[2],red[3]));
    __syncthreads();
    float e = (j < 197) ? __expf(v - m) : 0.f;
    float ssum = e;
    for (int off = 32; off; off >>= 1) ssum += __shfl_down(ssum, off);
    if (lane == 0) red[wid] = ssum;
    __syncthreads();
    float tot = red[0]+red[1]+red[2]+red[3];
    if (j < 197) sp[j] = e / tot;
}

// ---------------------------------------------------------------------------
// fc2 split-K combine: x += sum_s part[s] + bias
// ---------------------------------------------------------------------------
__global__ __launch_bounds__(256) void fc2_combine_k(
    const float* __restrict__ part, const float* __restrict__ bias,
    float* __restrict__ x)
{
    int idx = blockIdx.x*256 + threadIdx.x;
    if (idx >= 394*384) return;
    int n = idx % 384;
    const long MN = 394L*384;
    float v = part[idx] + part[idx+MN] + part[idx+2*MN] + part[idx+3*MN];
    x[idx] += v + bias[n];
}

// ---------------------------------------------------------------------------
extern "C" void kernel_launch(void* const* d_in, const int* in_sizes, int n_in,
                              void* d_out, int out_size, void* d_ws, size_t ws_size,
                              hipStream_t stream)
{
    const float* img      = (const float*)d_in[0];
    // d_in[1] segments: regular 16x16 grid (argsort(stable) == row-major block order)
    const float* fp_w     = (const float*)d_in[2];
    const float* fp_b     = (const float*)d_in[3];
    const float* ap_in_w  = (const float*)d_in[4];
    const float* ap_in_b  = (const float*)d_in[5];
    const float* ap_out_w = (const float*)d_in[6];
    const float* ap_out_b = (const float*)d_in[7];
    const float* cls_tok  = (const float*)d_in[8];
    const float* pos_emb  = (const float*)d_in[9];
    const float* ln1_g    = (const float*)d_in[10];
    const float* ln1_b    = (const float*)d_in[11];
    const float* qkv_w    = (const float*)d_in[12];
    const float* qkv_b    = (const float*)d_in[13];
    const float* proj_w   = (const float*)d_in[14];
    const float* proj_b   = (const float*)d_in[15];
    const float* ln2_g    = (const float*)d_in[16];
    const float* ln2_b    = (const float*)d_in[17];
    const float* fc1_w    = (const float*)d_in[18];
    const float* fc1_b    = (const float*)d_in[19];
    const float* fc2_w    = (const float*)d_in[20];
    const float* fc2_b    = (const float*)d_in[21];
    const float* norm_g   = (const float*)d_in[22];
    const float* norm_b   = (const float*)d_in[23];
    const float* head_w   = (const float*)d_in[24];
    const float* head_b   = (const float*)d_in[25];
    (void)in_sizes; (void)n_in; (void)out_size; (void)ws_size;
    float* out = (float*)d_out;

    float* ws = (float*)d_ws;
    size_t off = 0;
    auto alloc = [&](size_t nfl) { float* p = ws + off; off += (nfl + 63) & ~(size_t)63; return p; };
    float* W2     = alloc(1152*3);
    float* b2     = alloc(1152);
    float* hGm    = alloc(64);
    float* pooled = alloc(392L*384);
    float* tok    = alloc(392L*384);
    float* x      = alloc(394L*384);
    float* xn     = alloc(394L*384);
    float* qkvb   = alloc(394L*1152);
    float* scores = alloc(12L*197*197);
    float* attn   = alloc(394L*384);
    float* hbuf   = alloc(394L*1536);
    float* part   = alloc(4L*394*384);

    // ---- tokenizer ----
    prep_w2_k<<<5, 256, 0, stream>>>(ap_in_w, ap_in_b, fp_w, fp_b, W2, b2);
    prep_head_k<<<4, 64, 0, stream>>>(W2, b2, hGm);
    tok_attn_k<<<dim3(196,4,2), 256, 0, stream>>>(img, hGm, W2, b2, pooled);
    // out-proj: tok = pooled @ ap_out_w^T + ap_out_b
    launch_gemm<false,false,false>(stream, pooled, ap_out_w, ap_out_b, nullptr, tok,
        392, 384, 384, 384, 384, 384, 1.f, 1, 1, 0,0,0,0,0,0, 0);
    build_x0_k<<<(2*197*384 + 255)/256, 256, 0, stream>>>(tok, cls_tok, pos_emb, x);

    // ---- ViT trunk ----
    for (int i = 0; i < 12; ++i) {
        ln_k<<<394, 128, 0, stream>>>(x, ln1_g + i*384, ln1_b + i*384, xn);
        launch_gemm<false,false,false>(stream, xn, qkv_w + (long)i*1152*384,
            qkv_b + i*1152, nullptr, qkvb,
            394, 1152, 384, 384, 384, 1152, 1.f, 1, 1, 0,0,0,0,0,0, 0);
        // scores = Q K^T / 8 for 12 (b,h) batches
        launch_gemm<false,false,false>(stream, qkvb, qkvb + 384, nullptr, nullptr, scores,
            197, 197, 64, 1152, 1152, 197, 0.125f, 12, 6,
            197L*1152, 64L, 197L*1152, 64L, 6L*197*197, 197L*197, 0);
        softmax_k<<<12*197, 256, 0, stream>>>(scores);
        // attn = P @ V  (B transposed access into qkv V-part)
        launch_gemm<true,false,false>(stream, scores, qkvb + 768, nullptr, nullptr, attn,
            197, 64, 197, 197, 1152, 384, 1.f, 12, 6,
            6L*197*197, 197L*197, 197L*1152, 64L, 197L*384, 64L, 0);
        // x = x + attn @ proj_w^T + proj_b
        launch_gemm<false,true,false>(stream, attn, proj_w + (long)i*384*384,
            proj_b + i*384, x, x,
            394, 384, 384, 384, 384, 384, 1.f, 1, 1, 0,0,0,0,0,0, 0);
        ln_k<<<394, 128, 0, stream>>>(x, ln2_g + i*384, ln2_b + i*384, xn);
        // h = gelu(xn @ fc1_w^T + fc1_b)
        launch_gemm<false,false,true>(stream, xn, fc1_w + (long)i*1536*384,
            fc1_b + i*1536, nullptr, hbuf,
            394, 1536, 384, 384, 384, 1536, 1.f, 1, 1, 0,0,0,0,0,0, 0);
        // fc2 split-K (4 slices of 384)
        launch_gemm<false,false,false>(stream, hbuf, fc2_w + (long)i*384*1536,
            nullptr, nullptr, part,
            394, 384, 1536, 1536, 1536, 384, 1.f, 4, 4,
            0,0, 0,0, 0, 394L*384, 384);
        fc2_combine_k<<<(394*384 + 255)/256, 256, 0, stream>>>(part, fc2_b + i*384, x);
    }

    // ---- head ----
    ln_k<<<394, 128, 0, stream>>>(x, norm_g, norm_b, xn);
    // out[2,1000] = xn[cls rows] @ head_w^T + head_b  (rows 0 and 197 via lda)
    launch_gemm<false,false,false>(stream, xn, head_w, head_b, nullptr, out,
        2, 1000, 384, 197*384, 384, 1000, 1.f, 1, 1, 0,0,0,0,0,0, 0);
}

// Round 2
// 1482.602 us; speedup vs baseline: 2.5077x; 2.5077x over previous
//
#include <hip/hip_runtime.h>
#include <hip/hip_bf16.h>
#include <math.h>

// ---------------------------------------------------------------------------
// Model dims: B=2, Cn=3, HI=WI=224, S=196, P=256, D=384, H_TOK=4
// DEPTH=12, H_VIT=6 (dh=64), HID=1536, NCLS=1000
// ---------------------------------------------------------------------------

typedef __attribute__((ext_vector_type(8))) short short8b;
typedef __attribute__((ext_vector_type(4))) float f32x4;

static __device__ __forceinline__ float gelu_exact(float v) {
    return 0.5f * v * (1.0f + erff(v * 0.70710678118654752440f));
}

// ---------------------------------------------------------------------------
// f32 -> bf16 conversion (n % 4 == 0)
// ---------------------------------------------------------------------------
__global__ __launch_bounds__(256) void cvt_bf16_k(
    const float* __restrict__ src, __hip_bfloat16* __restrict__ dst, int n)
{
    int i = (blockIdx.x * 256 + threadIdx.x) * 4;
    if (i >= n) return;
    float4 v = *reinterpret_cast<const float4*>(src + i);
    dst[i+0] = __float2bfloat16(v.x);
    dst[i+1] = __float2bfloat16(v.y);
    dst[i+2] = __float2bfloat16(v.z);
    dst[i+3] = __float2bfloat16(v.w);
}

// ---------------------------------------------------------------------------
// prep: W2[1152][3] = ap_in_w @ fp_w ; b2[1152] = ap_in_b + ap_in_w @ fp_b
// ---------------------------------------------------------------------------
__global__ __launch_bounds__(256) void prep_w2_k(
    const float* __restrict__ ap_in_w, const float* __restrict__ ap_in_b,
    const float* __restrict__ fp_w, const float* __restrict__ fp_b,
    float* __restrict__ W2, float* __restrict__ b2)
{
    int o = blockIdx.x * 256 + threadIdx.x;
    if (o >= 1152) return;
    const float* ar = ap_in_w + (long)o * 384;
    float a0 = 0.f, a1 = 0.f, a2 = 0.f, ab = ap_in_b[o];
    for (int d = 0; d < 384; ++d) {
        float aw = ar[d];
        a0 = fmaf(aw, fp_w[d*3+0], a0);
        a1 = fmaf(aw, fp_w[d*3+1], a1);
        a2 = fmaf(aw, fp_w[d*3+2], a2);
        ab = fmaf(aw, fp_b[d], ab);
    }
    W2[o*3+0] = a0; W2[o*3+1] = a1; W2[o*3+2] = a2; b2[o] = ab;
}

// ---------------------------------------------------------------------------
// prep per-head bilinear form (scaled by 1/sqrt(96))
// ---------------------------------------------------------------------------
__global__ __launch_bounds__(64) void prep_head_k(
    const float* __restrict__ W2, const float* __restrict__ b2,
    float* __restrict__ hGm)
{
    int h = blockIdx.x;
    int lane = threadIdx.x;
    float G00=0,G01=0,G02=0,G10=0,G11=0,G12=0,G20=0,G21=0,G22=0;
    float u0=0,u1=0,u2=0,w0=0,w1=0,w2=0,c0=0;
    for (int d = lane; d < 96; d += 64) {
        int oq = h*96 + d, ok = 384 + h*96 + d;
        float q0=W2[oq*3],q1=W2[oq*3+1],q2=W2[oq*3+2];
        float k0=W2[ok*3],k1=W2[ok*3+1],k2=W2[ok*3+2];
        float bq=b2[oq], bk=b2[ok];
        G00=fmaf(q0,k0,G00); G01=fmaf(q0,k1,G01); G02=fmaf(q0,k2,G02);
        G10=fmaf(q1,k0,G10); G11=fmaf(q1,k1,G11); G12=fmaf(q1,k2,G12);
        G20=fmaf(q2,k0,G20); G21=fmaf(q2,k1,G21); G22=fmaf(q2,k2,G22);
        u0=fmaf(q0,bk,u0); u1=fmaf(q1,bk,u1); u2=fmaf(q2,bk,u2);
        w0=fmaf(k0,bq,w0); w1=fmaf(k1,bq,w1); w2=fmaf(k2,bq,w2);
        c0=fmaf(bq,bk,c0);
    }
    float vals[16] = {G00,G01,G02,u0, G10,G11,G12,u1, G20,G21,G22,u2, w0,w1,w2,c0};
    const float sc = 0.10206207261596577f; // 1/sqrt(96)
    #pragma unroll
    for (int q = 0; q < 16; ++q) {
        float v = vals[q];
        for (int off = 32; off; off >>= 1) v += __shfl_down(v, off);
        if (lane == 0) hGm[h*16 + q] = v * sc;
    }
}

// ---------------------------------------------------------------------------
// Tokenizer attention, one block per (segment s, head h, batch b).
// ---------------------------------------------------------------------------
__global__ __launch_bounds__(256) void tok_attn_k(
    const float* __restrict__ img, const float* __restrict__ hGm,
    const float* __restrict__ W2, const float* __restrict__ b2,
    float* __restrict__ pooled)
{
    int s = blockIdx.x, h = blockIdx.y, b = blockIdx.z;
    int t = threadIdx.x;
    __shared__ float4 pxm[256];
    __shared__ float4 ylds[256];
    __shared__ float  rl[256];
    __shared__ float  Ash[256];
    __shared__ float  tsum[3];

    int gy = s / 14, gx = s - gy*14;
    int row = gy*16 + (t >> 4), col = gx*16 + (t & 15);
    long base = ((long)b*3*224 + row)*224 + col;
    float p0 = img[base];
    float p1 = img[base + 224*224];
    float p2 = img[base + 2*224*224];

    const float4* M4 = reinterpret_cast<const float4*>(hGm) + h*4;
    float4 r0 = M4[0], r1 = M4[1], r2 = M4[2], r3 = M4[3];
    float y0 = fmaf(p0,r0.x, fmaf(p1,r0.y, fmaf(p2,r0.z, r0.w)));
    float y1 = fmaf(p0,r1.x, fmaf(p1,r1.y, fmaf(p2,r1.z, r1.w)));
    float y2 = fmaf(p0,r2.x, fmaf(p1,r2.y, fmaf(p2,r2.z, r2.w)));
    float y3 = fmaf(p0,r3.x, fmaf(p1,r3.y, fmaf(p2,r3.z, r3.w)));
    ylds[t] = make_float4(y0,y1,y2,y3);
    pxm[t]  = make_float4(p0,p1,p2,0.f);
    __syncthreads();

    float mx = -1e30f;
    #pragma unroll 4
    for (int j = 0; j < 256; ++j) {
        float4 Y = ylds[j];
        float scr = fmaf(p0,Y.x, fmaf(p1,Y.y, fmaf(p2,Y.z, Y.w)));
        mx = fmaxf(mx, scr);
    }
    float l = 0.f;
    #pragma unroll 4
    for (int j = 0; j < 256; ++j) {
        float4 Y = ylds[j];
        float scr = fmaf(p0,Y.x, fmaf(p1,Y.y, fmaf(p2,Y.z, Y.w)));
        l += __expf(scr - mx);
    }
    pxm[t].w = mx;
    rl[t] = 1.f / l;
    __syncthreads();

    float Aj = 0.f;
    #pragma unroll 4
    for (int i = 0; i < 256; ++i) {
        float4 q = pxm[i];
        float scr = fmaf(q.x,y0, fmaf(q.y,y1, fmaf(q.z,y2, y3)));
        Aj += __expf(scr - q.w) * rl[i];
    }
    Ash[t] = Aj;
    __syncthreads();

    int w = t >> 6, lane = t & 63;
    if (w < 3) {
        float prt = 0.f;
        for (int j = lane; j < 256; j += 64) {
            const float* pj = reinterpret_cast<const float*>(&pxm[j]);
            prt = fmaf(Ash[j], pj[w], prt);
        }
        for (int off = 32; off; off >>= 1) prt += __shfl_down(prt, off);
        if (lane == 0) tsum[w] = prt;
    }
    __syncthreads();

    if (t < 96) {
        int o = 768 + h*96 + t;
        float v = (W2[o*3]*tsum[0] + W2[o*3+1]*tsum[1] + W2[o*3+2]*tsum[2]) * (1.f/256.f)
                  + b2[o];
        pooled[((long)(b*196 + s))*384 + h*96 + t] = v;
    }
}

// ---------------------------------------------------------------------------
// Generic f32 GEMM (tokenizer out-proj, scores, PV, head).
// ---------------------------------------------------------------------------
template<bool BT, bool RES, bool GEL, bool OBF>
__global__ __launch_bounds__(256) void gemm64_k(
    const float* __restrict__ A, const float* __restrict__ W,
    const float* __restrict__ bias, const float* __restrict__ resid,
    void* __restrict__ Cv, int M, int N, int K, int lda, int ldw, int ldc,
    float alpha, int H, long sAb, long sAh, long sWb, long sWh, long sCb, long sCh,
    int kchunk)
{
    __shared__ float As[16][68];
    __shared__ float Bs[16][68];
    int z = blockIdx.z;
    int bi = z / H, hi = z - bi*H;
    A += bi*sAb + hi*sAh;
    W += bi*sWb + hi*sWh;
    long coff = bi*sCb + hi*sCh;
    const float* R = RES ? ((const float*)resid + coff) : nullptr;
    int ks = 0, ke = K;
    if (kchunk > 0) { ks = hi * kchunk; ke = min(K, ks + kchunk); }
    int m0 = blockIdx.x * 64, n0 = blockIdx.y * 64;
    int tid = threadIdx.x;
    int tx = tid & 15, ty = tid >> 4;
    float acc[4][4];
    #pragma unroll
    for (int i=0;i<4;++i)
        #pragma unroll
        for (int j=0;j<4;++j) acc[i][j]=0.f;

    for (int k0 = ks; k0 < ke; k0 += 16) {
        #pragma unroll
        for (int e = tid; e < 1024; e += 256) {
            int m = e >> 4, kk = e & 15;
            float v = 0.f;
            if (m0+m < M && k0+kk < ke) v = A[(long)(m0+m)*lda + k0+kk];
            As[kk][m] = v;
        }
        #pragma unroll
        for (int e = tid; e < 1024; e += 256) {
            float v = 0.f;
            if (!BT) {
                int n = e >> 4, kk = e & 15;
                if (n0+n < N && k0+kk < ke) v = W[(long)(n0+n)*ldw + k0+kk];
                Bs[kk][n] = v;
            } else {
                int n = e & 63, kk = e >> 6;
                if (k0+kk < ke && n0+n < N) v = W[(long)(k0+kk)*ldw + n0+n];
                Bs[kk][n] = v;
            }
        }
        __syncthreads();
        #pragma unroll
        for (int kk = 0; kk < 16; ++kk) {
            float4 av = *reinterpret_cast<const float4*>(&As[kk][ty*4]);
            float4 bv = *reinterpret_cast<const float4*>(&Bs[kk][tx*4]);
            float a[4] = {av.x,av.y,av.z,av.w};
            float b[4] = {bv.x,bv.y,bv.z,bv.w};
            #pragma unroll
            for (int i=0;i<4;++i)
                #pragma unroll
                for (int j=0;j<4;++j)
                    acc[i][j] = fmaf(a[i], b[j], acc[i][j]);
        }
        __syncthreads();
    }

    #pragma unroll
    for (int i=0;i<4;++i) {
        int m = m0 + ty*4 + i;
        if (m >= M) continue;
        #pragma unroll
        for (int j=0;j<4;++j) {
            int n = n0 + tx*4 + j;
            if (n >= N) continue;
            float v = acc[i][j] * alpha;
            if (bias) v += bias[n];
            if (GEL) v = gelu_exact(v);
            if (RES) v += R[(long)m*ldc + n];
            if (OBF) ((__hip_bfloat16*)Cv + coff)[(long)m*ldc + n] = __float2bfloat16(v);
            else     ((float*)Cv + coff)[(long)m*ldc + n] = v;
        }
    }
}

template<bool BT, bool RES, bool GEL, bool OBF>
static void launch_gemm(hipStream_t stream, const float* A, const float* W,
                        const float* bias, const float* resid, void* C,
                        int M, int N, int K, int lda, int ldw, int ldc,
                        float alpha, int gz, int H,
                        long sAb, long sAh, long sWb, long sWh, long sCb, long sCh,
                        int kchunk)
{
    dim3 grid((M+63)/64, (N+63)/64, gz);
    gemm64_k<BT,RES,GEL,OBF><<<grid, 256, 0, stream>>>(A, W, bias, resid, C, M, N, K,
        lda, ldw, ldc, alpha, H, sAb, sAh, sWb, sWh, sCb, sCh, kchunk);
}

// ---------------------------------------------------------------------------
// MFMA bf16 GEMM, 1 wave per block, 16x64 tile, LDS-free.
//   A: bf16 [M,K] lda (row-major).  W: bf16 [N,K] ldw (torch Linear layout).
//   Fragment maps (mfma_f32_16x16x32_bf16):
//     A: lane l -> row l&15,  k = (l>>4)*8 + e   (8 contiguous k -> short8 load)
//     B: lane l -> col l&15,  k = (l>>4)*8 + e
//     C: lane l -> col l&15,  row = (l>>4)*4 + reg
//   grid.z = split-K slices of kpart; f32 partial C offset z*sC.
// ---------------------------------------------------------------------------
template<bool GEL, bool RES, bool OBF>
__global__ __launch_bounds__(64) void gemm_mfma_k(
    const __hip_bfloat16* __restrict__ A, const __hip_bfloat16* __restrict__ W,
    const float* __restrict__ bias, const float* __restrict__ resid,
    void* __restrict__ Cv, int M, int N, int K, int lda, int ldw, int ldc,
    int kpart, long sC)
{
    int l = threadIdx.x;
    int m0 = blockIdx.x * 16, n0 = blockIdx.y * 64;
    int z = blockIdx.z;
    int ks = z * kpart;
    int klen = K - ks; if (klen > kpart) klen = kpart;

    int arow = m0 + (l & 15); if (arow >= M) arow = M - 1;
    const __hip_bfloat16* Ap = A + (long)arow * lda + ks + ((l >> 4) << 3);
    const __hip_bfloat16* W0 = W + (long)(n0 + (l & 15)) * ldw + ks + ((l >> 4) << 3);
    long wst = (long)ldw * 16;

    f32x4 acc[4];
    #pragma unroll
    for (int f = 0; f < 4; ++f) acc[f] = f32x4{0.f,0.f,0.f,0.f};

    int niter = klen >> 5;
    #pragma unroll 4
    for (int kt = 0; kt < niter; ++kt) {
        int k = kt << 5;
        short8b a  = *reinterpret_cast<const short8b*>(Ap + k);
        short8b b0 = *reinterpret_cast<const short8b*>(W0 + k);
        short8b b1 = *reinterpret_cast<const short8b*>(W0 + wst + k);
        short8b b2 = *reinterpret_cast<const short8b*>(W0 + 2*wst + k);
        short8b b3 = *reinterpret_cast<const short8b*>(W0 + 3*wst + k);
        acc[0] = __builtin_amdgcn_mfma_f32_16x16x32_bf16(a, b0, acc[0], 0, 0, 0);
        acc[1] = __builtin_amdgcn_mfma_f32_16x16x32_bf16(a, b1, acc[1], 0, 0, 0);
        acc[2] = __builtin_amdgcn_mfma_f32_16x16x32_bf16(a, b2, acc[2], 0, 0, 0);
        acc[3] = __builtin_amdgcn_mfma_f32_16x16x32_bf16(a, b3, acc[3], 0, 0, 0);
    }

    int cl = l & 15;
    int rbase = m0 + ((l >> 4) << 2);
    float* Cf = (float*)Cv + z * sC;
    __hip_bfloat16* Cb = (__hip_bfloat16*)Cv;
    #pragma unroll
    for (int f = 0; f < 4; ++f) {
        int n = n0 + f*16 + cl;
        float bv = bias ? bias[n] : 0.f;
        #pragma unroll
        for (int r = 0; r < 4; ++r) {
            int m = rbase + r;
            if (m >= M) continue;
            float v = acc[f][r] + bv;
            if (GEL) v = gelu_exact(v);
            if (RES) v += resid[(long)m*ldc + n];
            if (OBF) Cb[(long)m*ldc + n] = __float2bfloat16(v);
            else     Cf[(long)m*ldc + n] = v;
        }
    }
}

// ---------------------------------------------------------------------------
// x0 = concat(cls, tok) + pos_embed
// ---------------------------------------------------------------------------
__global__ __launch_bounds__(256) void build_x0_k(
    const float* __restrict__ tok, const float* __restrict__ cls,
    const float* __restrict__ pos, float* __restrict__ x)
{
    int idx = blockIdx.x*256 + threadIdx.x;
    if (idx >= 2*197*384) return;
    int d = idx % 384;
    int n = (idx / 384) % 197;
    int b = idx / (384*197);
    float v = (n == 0) ? cls[d] : tok[((long)b*196 + (n-1))*384 + d];
    x[idx] = v + pos[n*384 + d];
}

// ---------------------------------------------------------------------------
// LayerNorm over last dim 384; one block (128 threads) per row.
// BF: write bf16, else f32.
// ---------------------------------------------------------------------------
template<bool BF>
__global__ __launch_bounds__(128) void ln_k(
    const float* __restrict__ x, const float* __restrict__ g,
    const float* __restrict__ b, void* __restrict__ yv)
{
    long r = blockIdx.x;
    const float* xr = x + r*384;
    int t = threadIdx.x;
    float v0 = xr[t], v1 = xr[t+128], v2 = xr[t+256];
    __shared__ float red[2];
    int lane = t & 63, wid = t >> 6;
    float sm = v0+v1+v2;
    for (int off = 32; off; off >>= 1) sm += __shfl_down(sm, off);
    if (lane == 0) red[wid] = sm;
    __syncthreads();
    float mean = (red[0]+red[1]) * (1.f/384.f);
    __syncthreads();
    float d0=v0-mean, d1=v1-mean, d2=v2-mean;
    float s2 = d0*d0 + d1*d1 + d2*d2;
    for (int off = 32; off; off >>= 1) s2 += __shfl_down(s2, off);
    if (lane == 0) red[wid] = s2;
    __syncthreads();
    float var = (red[0]+red[1]) * (1.f/384.f);
    float rstd = rsqrtf(var + 1e-6f);
    float o0 = d0*rstd*g[t]     + b[t];
    float o1 = d1*rstd*g[t+128] + b[t+128];
    float o2 = d2*rstd*g[t+256] + b[t+256];
    if (BF) {
        __hip_bfloat16* yr = (__hip_bfloat16*)yv + r*384;
        yr[t] = __float2bfloat16(o0);
        yr[t+128] = __float2bfloat16(o1);
        yr[t+256] = __float2bfloat16(o2);
    } else {
        float* yr = (float*)yv + r*384;
        yr[t] = o0; yr[t+128] = o1; yr[t+256] = o2;
    }
}

// ---------------------------------------------------------------------------
// Row softmax over 197 columns, in place.
// ---------------------------------------------------------------------------
__global__ __launch_bounds__(256) void softmax_k(float* __restrict__ sc)
{
    long row = blockIdx.x;
    float* sp = sc + row*197;
    int j = threadIdx.x;
    float v = (j < 197) ? sp[j] : -1e30f;
    __shared__ float red[4];
    int lane = j & 63, wid = j >> 6;
    float m = v;
    for (int off = 32; off; off >>= 1) m = fmaxf(m, __shfl_down(m, off));
    if (lane == 0) red[wid] = m;
    __syncthreads();
    m = fmaxf(fmaxf(red[0],red[1]), fmaxf(red[2],red[3]));
    __syncthreads();
    float e = (j < 197) ? __expf(v - m) : 0.f;
    float ssum = e;
    for (int off = 32; off; off >>= 1) ssum += __shfl_down(ssum, off);
    if (lane == 0) red[wid] = ssum;
    __syncthreads();
    float tot = red[0]+red[1]+red[2]+red[3];
    if (j < 197) sp[j] = e / tot;
}

// ---------------------------------------------------------------------------
// fc2 split-K (2 slices) combine: x += part0 + part1 + bias
// ---------------------------------------------------------------------------
__global__ __launch_bounds__(256) void fc2_combine_k(
    const float* __restrict__ part, const float* __restrict__ bias,
    float* __restrict__ x)
{
    int idx = blockIdx.x*256 + threadIdx.x;
    if (idx >= 394*384) return;
    int n = idx % 384;
    const long MN = 394L*384;
    x[idx] += part[idx] + part[idx+MN] + bias[n];
}

// ---------------------------------------------------------------------------
extern "C" void kernel_launch(void* const* d_in, const int* in_sizes, int n_in,
                              void* d_out, int out_size, void* d_ws, size_t ws_size,
                              hipStream_t stream)
{
    const float* img      = (const float*)d_in[0];
    const float* fp_w     = (const float*)d_in[2];
    const float* fp_b     = (const float*)d_in[3];
    const float* ap_in_w  = (const float*)d_in[4];
    const float* ap_in_b  = (const float*)d_in[5];
    const float* ap_out_w = (const float*)d_in[6];
    const float* ap_out_b = (const float*)d_in[7];
    const float* cls_tok  = (const float*)d_in[8];
    const float* pos_emb  = (const float*)d_in[9];
    const float* ln1_g    = (const float*)d_in[10];
    const float* ln1_b    = (const float*)d_in[11];
    const float* qkv_w    = (const float*)d_in[12];
    const float* qkv_b    = (const float*)d_in[13];
    const float* proj_w   = (const float*)d_in[14];
    const float* proj_b   = (const float*)d_in[15];
    const float* ln2_g    = (const float*)d_in[16];
    const float* ln2_b    = (const float*)d_in[17];
    const float* fc1_w    = (const float*)d_in[18];
    const float* fc1_b    = (const float*)d_in[19];
    const float* fc2_w    = (const float*)d_in[20];
    const float* fc2_b    = (const float*)d_in[21];
    const float* norm_g   = (const float*)d_in[22];
    const float* norm_b   = (const float*)d_in[23];
    const float* head_w   = (const float*)d_in[24];
    const float* head_b   = (const float*)d_in[25];
    (void)in_sizes; (void)n_in; (void)out_size; (void)ws_size;
    float* out = (float*)d_out;

    float* ws = (float*)d_ws;
    size_t off = 0;
    auto alloc = [&](size_t nfl) { float* p = ws + off; off += (nfl + 63) & ~(size_t)63; return p; };
    float* W2     = alloc(1152*3);
    float* b2     = alloc(1152);
    float* hGm    = alloc(64);
    float* pooled = alloc(392L*384);
    float* tok    = alloc(392L*384);
    float* x      = alloc(394L*384);
    float* xnf    = alloc(394L*384);          // f32 (final LN only)
    float* qkvb   = alloc(394L*1152);
    float* scores = alloc(12L*197*197);
    float* part   = alloc(2L*394*384);
    __hip_bfloat16* xnb    = (__hip_bfloat16*)alloc(394L*384/2 + 64);
    __hip_bfloat16* attnb  = (__hip_bfloat16*)alloc(394L*384/2 + 64);
    __hip_bfloat16* hbufb  = (__hip_bfloat16*)alloc(394L*1536/2 + 64);
    __hip_bfloat16* qkvwb  = (__hip_bfloat16*)alloc(12L*1152*384/2);
    __hip_bfloat16* projwb = (__hip_bfloat16*)alloc(12L*384*384/2);
    __hip_bfloat16* fc1wb  = (__hip_bfloat16*)alloc(12L*1536*384/2);
    __hip_bfloat16* fc2wb  = (__hip_bfloat16*)alloc(12L*384*1536/2);

    // ---- weight conversion (once per call) ----
    {
        int n1 = 12*1152*384, n2 = 12*384*384, n3 = 12*1536*384;
        cvt_bf16_k<<<(n1/4 + 255)/256, 256, 0, stream>>>(qkv_w,  qkvwb,  n1);
        cvt_bf16_k<<<(n2/4 + 255)/256, 256, 0, stream>>>(proj_w, projwb, n2);
        cvt_bf16_k<<<(n3/4 + 255)/256, 256, 0, stream>>>(fc1_w,  fc1wb,  n3);
        cvt_bf16_k<<<(n3/4 + 255)/256, 256, 0, stream>>>(fc2_w,  fc2wb,  n3);
    }

    // ---- tokenizer ----
    prep_w2_k<<<5, 256, 0, stream>>>(ap_in_w, ap_in_b, fp_w, fp_b, W2, b2);
    prep_head_k<<<4, 64, 0, stream>>>(W2, b2, hGm);
    tok_attn_k<<<dim3(196,4,2), 256, 0, stream>>>(img, hGm, W2, b2, pooled);
    launch_gemm<false,false,false,false>(stream, pooled, ap_out_w, ap_out_b, nullptr, tok,
        392, 384, 384, 384, 384, 384, 1.f, 1, 1, 0,0,0,0,0,0, 0);
    build_x0_k<<<(2*197*384 + 255)/256, 256, 0, stream>>>(tok, cls_tok, pos_emb, x);

    // ---- ViT trunk ----
    for (int i = 0; i < 12; ++i) {
        ln_k<true><<<394, 128, 0, stream>>>(x, ln1_g + i*384, ln1_b + i*384, xnb);
        // qkvb = xn @ qkv_w^T + qkv_b   (f32 out for attention core)
        gemm_mfma_k<false,false,false><<<dim3(25,18,1), 64, 0, stream>>>(
            xnb, qkvwb + (long)i*1152*384, qkv_b + i*1152, nullptr, qkvb,
            394, 1152, 384, 384, 384, 1152, 384, 0);
        // scores = Q K^T / 8 for 12 (b,h)
        launch_gemm<false,false,false,false>(stream, qkvb, qkvb + 384, nullptr, nullptr, scores,
            197, 197, 64, 1152, 1152, 197, 0.125f, 12, 6,
            197L*1152, 64L, 197L*1152, 64L, 6L*197*197, 197L*197, 0);
        softmax_k<<<12*197, 256, 0, stream>>>(scores);
        // attn = P @ V  -> bf16
        launch_gemm<true,false,false,true>(stream, scores, qkvb + 768, nullptr, nullptr, attnb,
            197, 64, 197, 197, 1152, 384, 1.f, 12, 6,
            6L*197*197, 197L*197, 197L*1152, 64L, 197L*384, 64L, 0);
        // x += attn @ proj_w^T + proj_b
        gemm_mfma_k<false,true,false><<<dim3(25,6,1), 64, 0, stream>>>(
            attnb, projwb + (long)i*384*384, proj_b + i*384, x, x,
            394, 384, 384, 384, 384, 384, 384, 0);
        ln_k<true><<<394, 128, 0, stream>>>(x, ln2_g + i*384, ln2_b + i*384, xnb);
        // hbuf = gelu(xn @ fc1_w^T + fc1_b) -> bf16
        gemm_mfma_k<true,false,true><<<dim3(25,24,1), 64, 0, stream>>>(
            xnb, fc1wb + (long)i*1536*384, fc1_b + i*1536, nullptr, hbufb,
            394, 1536, 384, 384, 384, 1536, 384, 0);
        // fc2 split-K (2 x 768) partials
        gemm_mfma_k<false,false,false><<<dim3(25,6,2), 64, 0, stream>>>(
            hbufb, fc2wb + (long)i*384*1536, nullptr, nullptr, part,
            394, 384, 1536, 1536, 1536, 384, 768, 394L*384);
        fc2_combine_k<<<(394*384 + 255)/256, 256, 0, stream>>>(part, fc2_b + i*384, x);
    }

    // ---- head ----
    ln_k<false><<<394, 128, 0, stream>>>(x, norm_g, norm_b, xnf);
    launch_gemm<false,false,false,false>(stream, xnf, head_w, head_b, nullptr, out,
        2, 1000, 384, 197*384, 384, 1000, 1.f, 1, 1, 0,0,0,0,0,0, 0);
}

// Round 3
// 985.076 us; speedup vs baseline: 3.7742x; 1.5051x over previous
//
#include <hip/hip_runtime.h>
#include <hip/hip_bf16.h>
#include <math.h>

// ---------------------------------------------------------------------------
// Model dims: B=2, Cn=3, HI=WI=224, S=196, P=256, D=384, H_TOK=4
// DEPTH=12, H_VIT=6 (dh=64), HID=1536, NCLS=1000
// ---------------------------------------------------------------------------

typedef __attribute__((ext_vector_type(8))) short short8b;
typedef __attribute__((ext_vector_type(4))) float f32x4;

static __device__ __forceinline__ float gelu_exact(float v) {
    return 0.5f * v * (1.0f + erff(v * 0.70710678118654752440f));
}
static __device__ __forceinline__ short bf16s(float f) {
    __hip_bfloat16 h = __float2bfloat16(f);
    return *reinterpret_cast<short*>(&h);
}

// ---------------------------------------------------------------------------
// f32 -> bf16 conversion (n % 4 == 0)
// ---------------------------------------------------------------------------
__global__ __launch_bounds__(256) void cvt_bf16_k(
    const float* __restrict__ src, __hip_bfloat16* __restrict__ dst, int n)
{
    int i = (blockIdx.x * 256 + threadIdx.x) * 4;
    if (i >= n) return;
    float4 v = *reinterpret_cast<const float4*>(src + i);
    dst[i+0] = __float2bfloat16(v.x);
    dst[i+1] = __float2bfloat16(v.y);
    dst[i+2] = __float2bfloat16(v.z);
    dst[i+3] = __float2bfloat16(v.w);
}

// ---------------------------------------------------------------------------
// zero vT key-pad region: keys 197..223 for all [12][64] rows
// ---------------------------------------------------------------------------
__global__ __launch_bounds__(256) void zero_vtpad_k(__hip_bfloat16* __restrict__ vT)
{
    int i = blockIdx.x * 256 + threadIdx.x;
    if (i >= 12*64*27) return;
    int c = i % 27, r = i / 27;
    vT[(long)r*224 + 197 + c] = __float2bfloat16(0.f);
}

// ---------------------------------------------------------------------------
// prep: W2[1152][3] = ap_in_w @ fp_w ; b2[1152] = ap_in_b + ap_in_w @ fp_b
// ---------------------------------------------------------------------------
__global__ __launch_bounds__(256) void prep_w2_k(
    const float* __restrict__ ap_in_w, const float* __restrict__ ap_in_b,
    const float* __restrict__ fp_w, const float* __restrict__ fp_b,
    float* __restrict__ W2, float* __restrict__ b2)
{
    int o = blockIdx.x * 256 + threadIdx.x;
    if (o >= 1152) return;
    const float* ar = ap_in_w + (long)o * 384;
    float a0 = 0.f, a1 = 0.f, a2 = 0.f, ab = ap_in_b[o];
    for (int d = 0; d < 384; ++d) {
        float aw = ar[d];
        a0 = fmaf(aw, fp_w[d*3+0], a0);
        a1 = fmaf(aw, fp_w[d*3+1], a1);
        a2 = fmaf(aw, fp_w[d*3+2], a2);
        ab = fmaf(aw, fp_b[d], ab);
    }
    W2[o*3+0] = a0; W2[o*3+1] = a1; W2[o*3+2] = a2; b2[o] = ab;
}

// ---------------------------------------------------------------------------
// prep per-head bilinear form (scaled by 1/sqrt(96))
// ---------------------------------------------------------------------------
__global__ __launch_bounds__(64) void prep_head_k(
    const float* __restrict__ W2, const float* __restrict__ b2,
    float* __restrict__ hGm)
{
    int h = blockIdx.x;
    int lane = threadIdx.x;
    float G00=0,G01=0,G02=0,G10=0,G11=0,G12=0,G20=0,G21=0,G22=0;
    float u0=0,u1=0,u2=0,w0=0,w1=0,w2=0,c0=0;
    for (int d = lane; d < 96; d += 64) {
        int oq = h*96 + d, ok = 384 + h*96 + d;
        float q0=W2[oq*3],q1=W2[oq*3+1],q2=W2[oq*3+2];
        float k0=W2[ok*3],k1=W2[ok*3+1],k2=W2[ok*3+2];
        float bq=b2[oq], bk=b2[ok];
        G00=fmaf(q0,k0,G00); G01=fmaf(q0,k1,G01); G02=fmaf(q0,k2,G02);
        G10=fmaf(q1,k0,G10); G11=fmaf(q1,k1,G11); G12=fmaf(q1,k2,G12);
        G20=fmaf(q2,k0,G20); G21=fmaf(q2,k1,G21); G22=fmaf(q2,k2,G22);
        u0=fmaf(q0,bk,u0); u1=fmaf(q1,bk,u1); u2=fmaf(q2,bk,u2);
        w0=fmaf(k0,bq,w0); w1=fmaf(k1,bq,w1); w2=fmaf(k2,bq,w2);
        c0=fmaf(bq,bk,c0);
    }
    float vals[16] = {G00,G01,G02,u0, G10,G11,G12,u1, G20,G21,G22,u2, w0,w1,w2,c0};
    const float sc = 0.10206207261596577f; // 1/sqrt(96)
    #pragma unroll
    for (int q = 0; q < 16; ++q) {
        float v = vals[q];
        for (int off = 32; off; off >>= 1) v += __shfl_down(v, off);
        if (lane == 0) hGm[h*16 + q] = v * sc;
    }
}

// ---------------------------------------------------------------------------
// Tokenizer attention, one block per (segment s, head h, batch b).
// Writes pooled (pre out-proj) as bf16.
// ---------------------------------------------------------------------------
__global__ __launch_bounds__(256) void tok_attn_k(
    const float* __restrict__ img, const float* __restrict__ hGm,
    const float* __restrict__ W2, const float* __restrict__ b2,
    __hip_bfloat16* __restrict__ pooledb)
{
    int s = blockIdx.x, h = blockIdx.y, b = blockIdx.z;
    int t = threadIdx.x;
    __shared__ float4 pxm[256];
    __shared__ float4 ylds[256];
    __shared__ float  rl[256];
    __shared__ float  Ash[256];
    __shared__ float  tsum[3];

    int gy = s / 14, gx = s - gy*14;
    int row = gy*16 + (t >> 4), col = gx*16 + (t & 15);
    long base = ((long)b*3*224 + row)*224 + col;
    float p0 = img[base];
    float p1 = img[base + 224*224];
    float p2 = img[base + 2*224*224];

    const float4* M4 = reinterpret_cast<const float4*>(hGm) + h*4;
    float4 r0 = M4[0], r1 = M4[1], r2 = M4[2], r3 = M4[3];
    float y0 = fmaf(p0,r0.x, fmaf(p1,r0.y, fmaf(p2,r0.z, r0.w)));
    float y1 = fmaf(p0,r1.x, fmaf(p1,r1.y, fmaf(p2,r1.z, r1.w)));
    float y2 = fmaf(p0,r2.x, fmaf(p1,r2.y, fmaf(p2,r2.z, r2.w)));
    float y3 = fmaf(p0,r3.x, fmaf(p1,r3.y, fmaf(p2,r3.z, r3.w)));
    ylds[t] = make_float4(y0,y1,y2,y3);
    pxm[t]  = make_float4(p0,p1,p2,0.f);
    __syncthreads();

    float mx = -1e30f;
    #pragma unroll 4
    for (int j = 0; j < 256; ++j) {
        float4 Y = ylds[j];
        float scr = fmaf(p0,Y.x, fmaf(p1,Y.y, fmaf(p2,Y.z, Y.w)));
        mx = fmaxf(mx, scr);
    }
    float l = 0.f;
    #pragma unroll 4
    for (int j = 0; j < 256; ++j) {
        float4 Y = ylds[j];
        float scr = fmaf(p0,Y.x, fmaf(p1,Y.y, fmaf(p2,Y.z, Y.w)));
        l += __expf(scr - mx);
    }
    pxm[t].w = mx;
    rl[t] = 1.f / l;
    __syncthreads();

    float Aj = 0.f;
    #pragma unroll 4
    for (int i = 0; i < 256; ++i) {
        float4 q = pxm[i];
        float scr = fmaf(q.x,y0, fmaf(q.y,y1, fmaf(q.z,y2, y3)));
        Aj += __expf(scr - q.w) * rl[i];
    }
    Ash[t] = Aj;
    __syncthreads();

    int w = t >> 6, lane = t & 63;
    if (w < 3) {
        float prt = 0.f;
        for (int j = lane; j < 256; j += 64) {
            const float* pj = reinterpret_cast<const float*>(&pxm[j]);
            prt = fmaf(Ash[j], pj[w], prt);
        }
        for (int off = 32; off; off >>= 1) prt += __shfl_down(prt, off);
        if (lane == 0) tsum[w] = prt;
    }
    __syncthreads();

    if (t < 96) {
        int o = 768 + h*96 + t;
        float v = (W2[o*3]*tsum[0] + W2[o*3+1]*tsum[1] + W2[o*3+2]*tsum[2]) * (1.f/256.f)
                  + b2[o];
        pooledb[((long)(b*196 + s))*384 + h*96 + t] = __float2bfloat16(v);
    }
}

// ---------------------------------------------------------------------------
// Generic f32 GEMM (head only now).
// ---------------------------------------------------------------------------
template<bool BT, bool RES, bool GEL, bool OBF>
__global__ __launch_bounds__(256) void gemm64_k(
    const float* __restrict__ A, const float* __restrict__ W,
    const float* __restrict__ bias, const float* __restrict__ resid,
    void* __restrict__ Cv, int M, int N, int K, int lda, int ldw, int ldc,
    float alpha, int H, long sAb, long sAh, long sWb, long sWh, long sCb, long sCh,
    int kchunk)
{
    __shared__ float As[16][68];
    __shared__ float Bs[16][68];
    int z = blockIdx.z;
    int bi = z / H, hi = z - bi*H;
    A += bi*sAb + hi*sAh;
    W += bi*sWb + hi*sWh;
    long coff = bi*sCb + hi*sCh;
    const float* R = RES ? ((const float*)resid + coff) : nullptr;
    int ks = 0, ke = K;
    if (kchunk > 0) { ks = hi * kchunk; ke = min(K, ks + kchunk); }
    int m0 = blockIdx.x * 64, n0 = blockIdx.y * 64;
    int tid = threadIdx.x;
    int tx = tid & 15, ty = tid >> 4;
    float acc[4][4];
    #pragma unroll
    for (int i=0;i<4;++i)
        #pragma unroll
        for (int j=0;j<4;++j) acc[i][j]=0.f;

    for (int k0 = ks; k0 < ke; k0 += 16) {
        #pragma unroll
        for (int e = tid; e < 1024; e += 256) {
            int m = e >> 4, kk = e & 15;
            float v = 0.f;
            if (m0+m < M && k0+kk < ke) v = A[(long)(m0+m)*lda + k0+kk];
            As[kk][m] = v;
        }
        #pragma unroll
        for (int e = tid; e < 1024; e += 256) {
            float v = 0.f;
            if (!BT) {
                int n = e >> 4, kk = e & 15;
                if (n0+n < N && k0+kk < ke) v = W[(long)(n0+n)*ldw + k0+kk];
                Bs[kk][n] = v;
            } else {
                int n = e & 63, kk = e >> 6;
                if (k0+kk < ke && n0+n < N) v = W[(long)(k0+kk)*ldw + n0+n];
                Bs[kk][n] = v;
            }
        }
        __syncthreads();
        #pragma unroll
        for (int kk = 0; kk < 16; ++kk) {
            float4 av = *reinterpret_cast<const float4*>(&As[kk][ty*4]);
            float4 bv = *reinterpret_cast<const float4*>(&Bs[kk][tx*4]);
            float a[4] = {av.x,av.y,av.z,av.w};
            float b[4] = {bv.x,bv.y,bv.z,bv.w};
            #pragma unroll
            for (int i=0;i<4;++i)
                #pragma unroll
                for (int j=0;j<4;++j)
                    acc[i][j] = fmaf(a[i], b[j], acc[i][j]);
        }
        __syncthreads();
    }

    #pragma unroll
    for (int i=0;i<4;++i) {
        int m = m0 + ty*4 + i;
        if (m >= M) continue;
        #pragma unroll
        for (int j=0;j<4;++j) {
            int n = n0 + tx*4 + j;
            if (n >= N) continue;
            float v = acc[i][j] * alpha;
            if (bias) v += bias[n];
            if (GEL) v = gelu_exact(v);
            if (RES) v += R[(long)m*ldc + n];
            if (OBF) ((__hip_bfloat16*)Cv + coff)[(long)m*ldc + n] = __float2bfloat16(v);
            else     ((float*)Cv + coff)[(long)m*ldc + n] = v;
        }
    }
}

// ---------------------------------------------------------------------------
// MFMA bf16 GEMM, 1 wave per block, 16x64 tile, LDS-free (validated R2).
// ---------------------------------------------------------------------------
template<bool GEL, bool RES, bool OBF>
__global__ __launch_bounds__(64) void gemm_mfma_k(
    const __hip_bfloat16* __restrict__ A, const __hip_bfloat16* __restrict__ W,
    const float* __restrict__ bias, const float* __restrict__ resid,
    void* __restrict__ Cv, int M, int N, int K, int lda, int ldw, int ldc,
    int kpart, long sC)
{
    int l = threadIdx.x;
    int m0 = blockIdx.x * 16, n0 = blockIdx.y * 64;
    int z = blockIdx.z;
    int ks = z * kpart;
    int klen = K - ks; if (klen > kpart) klen = kpart;

    int arow = m0 + (l & 15); if (arow >= M) arow = M - 1;
    const __hip_bfloat16* Ap = A + (long)arow * lda + ks + ((l >> 4) << 3);
    const __hip_bfloat16* W0 = W + (long)(n0 + (l & 15)) * ldw + ks + ((l >> 4) << 3);
    long wst = (long)ldw * 16;

    f32x4 acc[4];
    #pragma unroll
    for (int f = 0; f < 4; ++f) acc[f] = f32x4{0.f,0.f,0.f,0.f};

    int niter = klen >> 5;
    #pragma unroll 4
    for (int kt = 0; kt < niter; ++kt) {
        int k = kt << 5;
        short8b a  = *reinterpret_cast<const short8b*>(Ap + k);
        short8b b0 = *reinterpret_cast<const short8b*>(W0 + k);
        short8b b1 = *reinterpret_cast<const short8b*>(W0 + wst + k);
        short8b b2 = *reinterpret_cast<const short8b*>(W0 + 2*wst + k);
        short8b b3 = *reinterpret_cast<const short8b*>(W0 + 3*wst + k);
        acc[0] = __builtin_amdgcn_mfma_f32_16x16x32_bf16(a, b0, acc[0], 0, 0, 0);
        acc[1] = __builtin_amdgcn_mfma_f32_16x16x32_bf16(a, b1, acc[1], 0, 0, 0);
        acc[2] = __builtin_amdgcn_mfma_f32_16x16x32_bf16(a, b2, acc[2], 0, 0, 0);
        acc[3] = __builtin_amdgcn_mfma_f32_16x16x32_bf16(a, b3, acc[3], 0, 0, 0);
    }

    int cl = l & 15;
    int rbase = m0 + ((l >> 4) << 2);
    float* Cf = (float*)Cv + z * sC;
    __hip_bfloat16* Cb = (__hip_bfloat16*)Cv;
    #pragma unroll
    for (int f = 0; f < 4; ++f) {
        int n = n0 + f*16 + cl;
        float bv = bias ? bias[n] : 0.f;
        #pragma unroll
        for (int r = 0; r < 4; ++r) {
            int m = rbase + r;
            if (m >= M) continue;
            float v = acc[f][r] + bv;
            if (GEL) v = gelu_exact(v);
            if (RES) v += resid[(long)m*ldc + n];
            if (OBF) Cb[(long)m*ldc + n] = __float2bfloat16(v);
            else     Cf[(long)m*ldc + n] = v;
        }
    }
}

// ---------------------------------------------------------------------------
// Fused LayerNorm + MFMA GEMM. A = LN(x) computed on the fly (K=384 fixed).
// EPI=1: qkv scatter to qb/kb (x0.125 on q) /vT bf16.  EPI=2: gelu -> bf16 C.
// 1 wave per block, 16x64 tile. x: f32 [M][384].
// ---------------------------------------------------------------------------
template<int EPI>
__global__ __launch_bounds__(64) void ln_gemm_k(
    const float* __restrict__ x, const float* __restrict__ g,
    const float* __restrict__ b, const __hip_bfloat16* __restrict__ W,
    const float* __restrict__ bias,
    __hip_bfloat16* __restrict__ o0, __hip_bfloat16* __restrict__ o1,
    __hip_bfloat16* __restrict__ o2, int M, int N)
{
    int l = threadIdx.x;
    int m0 = blockIdx.x * 16, n0 = blockIdx.y * 64;
    int cl = l & 15, hi = l >> 4;
    int row = m0 + cl; if (row >= M) row = M - 1;
    const float* xp = x + (long)row*384 + (hi << 3);

    // pass 1: row stats (4 lanes per row, shfl_xor 16/32 combine)
    float sum = 0.f, sq = 0.f;
    #pragma unroll
    for (int t = 0; t < 12; ++t) {
        float4 v0 = *reinterpret_cast<const float4*>(xp + t*32);
        float4 v1 = *reinterpret_cast<const float4*>(xp + t*32 + 4);
        sum += v0.x+v0.y+v0.z+v0.w + v1.x+v1.y+v1.z+v1.w;
        sq  += v0.x*v0.x+v0.y*v0.y+v0.z*v0.z+v0.w*v0.w
             + v1.x*v1.x+v1.y*v1.y+v1.z*v1.z+v1.w*v1.w;
    }
    sum += __shfl_xor(sum, 16); sum += __shfl_xor(sum, 32);
    sq  += __shfl_xor(sq, 16);  sq  += __shfl_xor(sq, 32);
    float mean = sum * (1.f/384.f);
    float var  = sq * (1.f/384.f) - mean*mean;
    float rstd = rsqrtf(var + 1e-6f);

    const __hip_bfloat16* Wp = W + (long)(n0 + cl)*384 + (hi << 3);
    f32x4 acc[4];
    #pragma unroll
    for (int f = 0; f < 4; ++f) acc[f] = f32x4{0.f,0.f,0.f,0.f};

    #pragma unroll 2
    for (int t = 0; t < 12; ++t) {
        int k = t*32 + (hi << 3);
        float4 v0 = *reinterpret_cast<const float4*>(xp + t*32);
        float4 v1 = *reinterpret_cast<const float4*>(xp + t*32 + 4);
        float4 g0 = *reinterpret_cast<const float4*>(g + k);
        float4 g1 = *reinterpret_cast<const float4*>(g + k + 4);
        float4 bb0 = *reinterpret_cast<const float4*>(b + k);
        float4 bb1 = *reinterpret_cast<const float4*>(b + k + 4);
        short8b a;
        a[0] = bf16s(fmaf((v0.x-mean)*rstd, g0.x, bb0.x));
        a[1] = bf16s(fmaf((v0.y-mean)*rstd, g0.y, bb0.y));
        a[2] = bf16s(fmaf((v0.z-mean)*rstd, g0.z, bb0.z));
        a[3] = bf16s(fmaf((v0.w-mean)*rstd, g0.w, bb0.w));
        a[4] = bf16s(fmaf((v1.x-mean)*rstd, g1.x, bb1.x));
        a[5] = bf16s(fmaf((v1.y-mean)*rstd, g1.y, bb1.y));
        a[6] = bf16s(fmaf((v1.z-mean)*rstd, g1.z, bb1.z));
        a[7] = bf16s(fmaf((v1.w-mean)*rstd, g1.w, bb1.w));
        short8b w0 = *reinterpret_cast<const short8b*>(Wp + t*32);
        short8b w1 = *reinterpret_cast<const short8b*>(Wp + 16L*384 + t*32);
        short8b w2 = *reinterpret_cast<const short8b*>(Wp + 32L*384 + t*32);
        short8b w3 = *reinterpret_cast<const short8b*>(Wp + 48L*384 + t*32);
        acc[0] = __builtin_amdgcn_mfma_f32_16x16x32_bf16(a, w0, acc[0], 0, 0, 0);
        acc[1] = __builtin_amdgcn_mfma_f32_16x16x32_bf16(a, w1, acc[1], 0, 0, 0);
        acc[2] = __builtin_amdgcn_mfma_f32_16x16x32_bf16(a, w2, acc[2], 0, 0, 0);
        acc[3] = __builtin_amdgcn_mfma_f32_16x16x32_bf16(a, w3, acc[3], 0, 0, 0);
    }

    int rb = hi << 2;
    #pragma unroll
    for (int f = 0; f < 4; ++f) {
        int n = n0 + f*16 + cl;
        float bv = bias[n];
        #pragma unroll
        for (int r = 0; r < 4; ++r) {
            int m = m0 + rb + r;
            if (m >= M) continue;
            float v = acc[f][r] + bv;
            if (EPI == 1) {
                int bb = (m >= 197) ? 1 : 0;
                int tokr = m - bb*197;
                if (n < 384) {
                    int h = n >> 6, ch = n & 63;
                    o0[((long)(bb*6 + h)*208 + tokr)*64 + ch] = __float2bfloat16(v * 0.125f);
                } else if (n < 768) {
                    int nn = n - 384, h = nn >> 6, ch = nn & 63;
                    o1[((long)(bb*6 + h)*208 + tokr)*64 + ch] = __float2bfloat16(v);
                } else {
                    int nn = n - 768, h = nn >> 6, ch = nn & 63;
                    o2[((long)(bb*6 + h)*64 + ch)*224 + tokr] = __float2bfloat16(v);
                }
            } else { // EPI == 2
                o0[(long)m*N + n] = __float2bfloat16(gelu_exact(v));
            }
        }
    }
}

// ---------------------------------------------------------------------------
// Fused flash attention (per layer): scores(MFMA) + softmax + PV(MFMA).
// grid: (13 q-tiles, 12 bh). 1 wave. qb/kb [12][208][64], vT [12][64][224].
// ---------------------------------------------------------------------------
__global__ __launch_bounds__(64) void attn_flash_k(
    const __hip_bfloat16* __restrict__ qb, const __hip_bfloat16* __restrict__ kb,
    const __hip_bfloat16* __restrict__ vT, __hip_bfloat16* __restrict__ attnb)
{
    __shared__ __align__(16) short lp[16*232];   // P tile bf16, padded stride
    int l = threadIdx.x;
    int qt = blockIdx.x, bh = blockIdx.y;
    int q0 = qt * 16;
    int cl = l & 15, hi = l >> 4;

    // zero P columns 208..223 (keys 197..207 get exp(-inf)=0 via f=12 writes)
    if (l < 32) {
        int row = l >> 1, hf = l & 1;
        *reinterpret_cast<int4*>(lp + row*232 + 208 + hf*8) = int4{0,0,0,0};
    }

    // ---- scores = Q K^T (scale already folded into Q) ----
    const __hip_bfloat16* Qp = qb + ((long)bh*208 + q0 + cl)*64 + (hi << 3);
    const __hip_bfloat16* Kp = kb + ((long)bh*208 + cl)*64 + (hi << 3);
    f32x4 s[13];
    #pragma unroll
    for (int f = 0; f < 13; ++f) s[f] = f32x4{0.f,0.f,0.f,0.f};
    #pragma unroll
    for (int kt = 0; kt < 2; ++kt) {
        short8b a = *reinterpret_cast<const short8b*>(Qp + kt*32);
        #pragma unroll
        for (int f = 0; f < 13; ++f) {
            short8b kk = *reinterpret_cast<const short8b*>(Kp + (long)f*16*64 + kt*32);
            s[f] = __builtin_amdgcn_mfma_f32_16x16x32_bf16(a, kk, s[f], 0, 0, 0);
        }
    }
    if (cl >= 5) s[12] = f32x4{-1e30f,-1e30f,-1e30f,-1e30f}; // cols 197..207

    // ---- softmax per row, write P bf16 to LDS ----
    #pragma unroll
    for (int r = 0; r < 4; ++r) {
        float m = s[0][r];
        #pragma unroll
        for (int f = 1; f < 13; ++f) m = fmaxf(m, s[f][r]);
        m = fmaxf(m, __shfl_xor(m, 1));
        m = fmaxf(m, __shfl_xor(m, 2));
        m = fmaxf(m, __shfl_xor(m, 4));
        m = fmaxf(m, __shfl_xor(m, 8));
        float e[13]; float sum = 0.f;
        #pragma unroll
        for (int f = 0; f < 13; ++f) { e[f] = __expf(s[f][r] - m); sum += e[f]; }
        sum += __shfl_xor(sum, 1);
        sum += __shfl_xor(sum, 2);
        sum += __shfl_xor(sum, 4);
        sum += __shfl_xor(sum, 8);
        float ri = 1.f / sum;
        int prow = (hi << 2) + r;
        #pragma unroll
        for (int f = 0; f < 13; ++f)
            lp[prow*232 + f*16 + cl] = bf16s(e[f] * ri);
    }
    __syncthreads();

    // ---- PV ----
    f32x4 o[4];
    #pragma unroll
    for (int f = 0; f < 4; ++f) o[f] = f32x4{0.f,0.f,0.f,0.f};
    const __hip_bfloat16* Vp = vT + ((long)bh*64 + cl)*224 + (hi << 3);
    #pragma unroll
    for (int kt = 0; kt < 7; ++kt) {
        short8b pa = *reinterpret_cast<const short8b*>(&lp[cl*232 + (hi << 3) + kt*32]);
        #pragma unroll
        for (int f2 = 0; f2 < 4; ++f2) {
            short8b vb = *reinterpret_cast<const short8b*>(Vp + (long)f2*16*224 + kt*32);
            o[f2] = __builtin_amdgcn_mfma_f32_16x16x32_bf16(pa, vb, o[f2], 0, 0, 0);
        }
    }

    int b = bh / 6, h = bh - b*6;
    #pragma unroll
    for (int f2 = 0; f2 < 4; ++f2) {
        int ch = h*64 + f2*16 + cl;
        #pragma unroll
        for (int r = 0; r < 4; ++r) {
            int qr = q0 + (hi << 2) + r;
            if (qr < 197)
                attnb[((long)(b*197 + qr))*384 + ch] = __float2bfloat16(o[f2][r]);
        }
    }
}

// ---------------------------------------------------------------------------
// x0 = concat(cls, tok) + pos_embed
// ---------------------------------------------------------------------------
__global__ __launch_bounds__(256) void build_x0_k(
    const float* __restrict__ tok, const float* __restrict__ cls,
    const float* __restrict__ pos, float* __restrict__ x)
{
    int idx = blockIdx.x*256 + threadIdx.x;
    if (idx >= 2*197*384) return;
    int d = idx % 384;
    int n = (idx / 384) % 197;
    int b = idx / (384*197);
    float v = (n == 0) ? cls[d] : tok[((long)b*196 + (n-1))*384 + d];
    x[idx] = v + pos[n*384 + d];
}

// ---------------------------------------------------------------------------
// LayerNorm (final norm only), f32 out.
// ---------------------------------------------------------------------------
__global__ __launch_bounds__(128) void ln_k(
    const float* __restrict__ x, const float* __restrict__ g,
    const float* __restrict__ b, float* __restrict__ y)
{
    long r = blockIdx.x;
    const float* xr = x + r*384;
    int t = threadIdx.x;
    float v0 = xr[t], v1 = xr[t+128], v2 = xr[t+256];
    __shared__ float red[2];
    int lane = t & 63, wid = t >> 6;
    float sm = v0+v1+v2;
    for (int off = 32; off; off >>= 1) sm += __shfl_down(sm, off);
    if (lane == 0) red[wid] = sm;
    __syncthreads();
    float mean = (red[0]+red[1]) * (1.f/384.f);
    __syncthreads();
    float d0=v0-mean, d1=v1-mean, d2=v2-mean;
    float s2 = d0*d0 + d1*d1 + d2*d2;
    for (int off = 32; off; off >>= 1) s2 += __shfl_down(s2, off);
    if (lane == 0) red[wid] = s2;
    __syncthreads();
    float var = (red[0]+red[1]) * (1.f/384.f);
    float rstd = rsqrtf(var + 1e-6f);
    y[r*384+t]     = d0*rstd*g[t]     + b[t];
    y[r*384+t+128] = d1*rstd*g[t+128] + b[t+128];
    y[r*384+t+256] = d2*rstd*g[t+256] + b[t+256];
}

// ---------------------------------------------------------------------------
extern "C" void kernel_launch(void* const* d_in, const int* in_sizes, int n_in,
                              void* d_out, int out_size, void* d_ws, size_t ws_size,
                              hipStream_t stream)
{
    const float* img      = (const float*)d_in[0];
    const float* fp_w     = (const float*)d_in[2];
    const float* fp_b     = (const float*)d_in[3];
    const float* ap_in_w  = (const float*)d_in[4];
    const float* ap_in_b  = (const float*)d_in[5];
    const float* ap_out_w = (const float*)d_in[6];
    const float* ap_out_b = (const float*)d_in[7];
    const float* cls_tok  = (const float*)d_in[8];
    const float* pos_emb  = (const float*)d_in[9];
    const float* ln1_g    = (const float*)d_in[10];
    const float* ln1_b    = (const float*)d_in[11];
    const float* qkv_w    = (const float*)d_in[12];
    const float* qkv_b    = (const float*)d_in[13];
    const float* proj_w   = (const float*)d_in[14];
    const float* proj_b   = (const float*)d_in[15];
    const float* ln2_g    = (const float*)d_in[16];
    const float* ln2_b    = (const float*)d_in[17];
    const float* fc1_w    = (const float*)d_in[18];
    const float* fc1_b    = (const float*)d_in[19];
    const float* fc2_w    = (const float*)d_in[20];
    const float* fc2_b    = (const float*)d_in[21];
    const float* norm_g   = (const float*)d_in[22];
    const float* norm_b   = (const float*)d_in[23];
    const float* head_w   = (const float*)d_in[24];
    const float* head_b   = (const float*)d_in[25];
    (void)in_sizes; (void)n_in; (void)out_size; (void)ws_size;
    float* out = (float*)d_out;

    float* ws = (float*)d_ws;
    size_t off = 0;
    auto alloc = [&](size_t nfl) { float* p = ws + off; off += (nfl + 63) & ~(size_t)63; return p; };
    float* W2     = alloc(1152*3);
    float* b2     = alloc(1152);
    float* hGm    = alloc(64);
    float* tok    = alloc(392L*384);
    float* x      = alloc(394L*384);
    float* xnf    = alloc(394L*384);
    __hip_bfloat16* pooledb = (__hip_bfloat16*)alloc(392L*384/2);
    __hip_bfloat16* attnb   = (__hip_bfloat16*)alloc(394L*384/2 + 64);
    __hip_bfloat16* hbufb   = (__hip_bfloat16*)alloc(394L*1536/2 + 64);
    __hip_bfloat16* qb      = (__hip_bfloat16*)alloc(12L*208*64/2);
    __hip_bfloat16* kb      = (__hip_bfloat16*)alloc(12L*208*64/2);
    __hip_bfloat16* vT      = (__hip_bfloat16*)alloc(12L*64*224/2);
    __hip_bfloat16* qkvwb   = (__hip_bfloat16*)alloc(12L*1152*384/2);
    __hip_bfloat16* projwb  = (__hip_bfloat16*)alloc(12L*384*384/2);
    __hip_bfloat16* fc1wb   = (__hip_bfloat16*)alloc(12L*1536*384/2);
    __hip_bfloat16* fc2wb   = (__hip_bfloat16*)alloc(12L*384*1536/2);
    __hip_bfloat16* apoutwb = (__hip_bfloat16*)alloc(384L*384/2);

    // ---- weight conversion + pad init ----
    {
        int n1 = 12*1152*384, n2 = 12*384*384, n3 = 12*1536*384, n4 = 384*384;
        cvt_bf16_k<<<(n1/4 + 255)/256, 256, 0, stream>>>(qkv_w,  qkvwb,  n1);
        cvt_bf16_k<<<(n2/4 + 255)/256, 256, 0, stream>>>(proj_w, projwb, n2);
        cvt_bf16_k<<<(n3/4 + 255)/256, 256, 0, stream>>>(fc1_w,  fc1wb,  n3);
        cvt_bf16_k<<<(n3/4 + 255)/256, 256, 0, stream>>>(fc2_w,  fc2wb,  n3);
        cvt_bf16_k<<<(n4/4 + 255)/256, 256, 0, stream>>>(ap_out_w, apoutwb, n4);
        zero_vtpad_k<<<(12*64*27 + 255)/256, 256, 0, stream>>>(vT);
    }

    // ---- tokenizer ----
    prep_w2_k<<<5, 256, 0, stream>>>(ap_in_w, ap_in_b, fp_w, fp_b, W2, b2);
    prep_head_k<<<4, 64, 0, stream>>>(W2, b2, hGm);
    tok_attn_k<<<dim3(196,4,2), 256, 0, stream>>>(img, hGm, W2, b2, pooledb);
    gemm_mfma_k<false,false,false><<<dim3(25,6,1), 64, 0, stream>>>(
        pooledb, apoutwb, ap_out_b, nullptr, tok,
        392, 384, 384, 384, 384, 384, 384, 0);
    build_x0_k<<<(2*197*384 + 255)/256, 256, 0, stream>>>(tok, cls_tok, pos_emb, x);

    // ---- ViT trunk (5 dispatches per layer) ----
    for (int i = 0; i < 12; ++i) {
        // LN1 + QKV + scatter to qb/kb/vT
        ln_gemm_k<1><<<dim3(25,18), 64, 0, stream>>>(
            x, ln1_g + i*384, ln1_b + i*384, qkvwb + (long)i*1152*384,
            qkv_b + i*1152, qb, kb, vT, 394, 1152);
        // fused attention -> attnb bf16
        attn_flash_k<<<dim3(13,12), 64, 0, stream>>>(qb, kb, vT, attnb);
        // x += attn @ proj_w^T + proj_b
        gemm_mfma_k<false,true,false><<<dim3(25,6,1), 64, 0, stream>>>(
            attnb, projwb + (long)i*384*384, proj_b + i*384, x, x,
            394, 384, 384, 384, 384, 384, 384, 0);
        // LN2 + FC1 + gelu -> hbufb bf16
        ln_gemm_k<2><<<dim3(25,24), 64, 0, stream>>>(
            x, ln2_g + i*384, ln2_b + i*384, fc1wb + (long)i*1536*384,
            fc1_b + i*1536, hbufb, nullptr, nullptr, 394, 1536);
        // x += hbuf @ fc2_w^T + fc2_b (full K)
        gemm_mfma_k<false,true,false><<<dim3(25,6,1), 64, 0, stream>>>(
            hbufb, fc2wb + (long)i*384*1536, fc2_b + i*384, x, x,
            394, 384, 1536, 1536, 1536, 384, 1536, 0);
    }

    // ---- head ----
    ln_k<<<394, 128, 0, stream>>>(x, norm_g, norm_b, xnf);
    gemm64_k<false,false,false,false><<<dim3(1,16,1), 256, 0, stream>>>(
        xnf, head_w, head_b, nullptr, out,
        2, 1000, 384, 197*384, 384, 1000, 1.f, 1, 0,0,0,0,0,0, 0);
}